// Round 12
// baseline (798.082 us; speedup 1.0000x reference)
//
#include <hip/hip_runtime.h>
#include <hip/hip_fp8.h>

#define N_NODES 86016
#define N_EDGES 4194304
#define HID 32
#define B_GR 1024
#define NPG 84
#define NEG 0.2f

#define NCH 512       // chunks
#define CHE 8192      // edges per chunk; NCH*CHE == N_EDGES
#define NB  512       // dst buckets
#define NPB 168       // nodes per bucket; NB*NPB == N_NODES
#define SRCMASK 0x1FFFF   // 17 bits (N_NODES < 2^17)

// ---- workspace layout (bytes) ----
// Edge record: int2 { src | (dn<<17), (bf16(ea.y)<<16)|bf16(ea.x) } = 8 B.
// hT: N x 32 fp8-e4m3 (32 B/row) = 2.75 MB -> fits per-XCD 4 MiB L2.
constexpr size_t O_REC   = 0;                                    // E * 8
constexpr size_t O_CM    = O_REC  + (size_t)N_EDGES * 8;         // NB*NCH int
constexpr size_t O_HT    = O_CM   + (size_t)NB * NCH * 4;        // N*32 fp8
constexpr size_t O_HB    = O_HT   + (size_t)N_NODES * HID;       // N*32 f32
constexpr size_t O_AS    = O_HB   + (size_t)N_NODES * HID * 4;   // N f32
constexpr size_t O_AD    = O_AS   + (size_t)N_NODES * 4;         // N f32
constexpr size_t O_ROW   = O_AD   + (size_t)N_NODES * 4;         // N+1 int
constexpr size_t O_BTOT  = O_ROW  + (size_t)(N_NODES + 1) * 4 + 12; // NB int
constexpr size_t O_BBASE = O_BTOT + (size_t)NB * 4;              // NB+1 int
constexpr size_t O_FOLD  = O_BBASE + (size_t)(NB + 1) * 4 + 12;  // 8 f32

__device__ __forceinline__ unsigned short f2bf(float f) {
    unsigned u = __float_as_uint(f);
    u += 0x7FFFu + ((u >> 16) & 1u);      // round-to-nearest-even
    return (unsigned short)(u >> 16);
}

// ---- CSR build, atomic-free (global), single 8B stream ----
__global__ __launch_bounds__(1024) void k_hist(const int* __restrict__ dst, int* __restrict__ cm) {
    __shared__ int cnt[NB];
    int t = threadIdx.x, c = blockIdx.x;
    if (t < NB) cnt[t] = 0;
    __syncthreads();
    int base = c * CHE;
#pragma unroll
    for (int k = 0; k < 8; ++k) {
        int d = dst[base + k * 1024 + t];
        atomicAdd(&cnt[(unsigned)d / NPB], 1);
    }
    __syncthreads();
    if (t < NB) cm[t * NCH + c] = cnt[t];
}

__global__ __launch_bounds__(512) void k_scanchunks(int* __restrict__ cm, int* __restrict__ btot) {
    __shared__ int sa[NCH], sb[NCH];
    int b = blockIdx.x, t = threadIdx.x;
    sa[t] = cm[b * NCH + t];
    __syncthreads();
    int* s = sa; int* d = sb;
    for (int off = 1; off < NCH; off <<= 1) {
        d[t] = s[t] + (t >= off ? s[t - off] : 0);
        __syncthreads();
        int* tmp = s; s = d; d = tmp;
    }
    cm[b * NCH + t] = t ? s[t - 1] : 0;
    if (t == 0) btot[b] = s[NCH - 1];
}

// bucket-total scan (+ inlined fold computation on threads 0..7)
__global__ void k_scanbuckets(const int* __restrict__ btot, int* __restrict__ bbase,
                              int* __restrict__ row,
                              const float* __restrict__ We, const float* __restrict__ ae,
                              float* __restrict__ fold) {
    __shared__ int sa[NB], sb[NB];
    int t = threadIdx.x;
    if (t < 8) {
        int l = t >> 1, c = t & 1;
        float s = 0.f;
        for (int j = 0; j < 32; ++j) s += We[l * 64 + c * 32 + j] * ae[l * 32 + j];
        fold[t] = s;
    }
    sa[t] = btot[t];
    __syncthreads();
    int* s = sa; int* d = sb;
    for (int off = 1; off < NB; off <<= 1) {
        d[t] = s[t] + (t >= off ? s[t - off] : 0);
        __syncthreads();
        int* tmp = s; s = d; d = tmp;
    }
    bbase[t] = t ? s[t - 1] : 0;
    if (t == NB - 1) { bbase[NB] = s[NB - 1]; row[N_NODES] = s[NB - 1]; }
}

// R8-style place: register-staged batch of 8 edges, rank in LDS, batched writes.
__global__ __launch_bounds__(1024) void k_place(const int* __restrict__ ei,
                                                const float2* __restrict__ ea,
                                                const int* __restrict__ cm,
                                                const int* __restrict__ bbase,
                                                int2* __restrict__ rec) {
    __shared__ int cnt[NB];
    __shared__ int base[NB];
    int t = threadIdx.x, c = blockIdx.x;
    if (t < NB) cnt[t] = 0;
    __syncthreads();
    int eb = c * CHE;
    int wd0[8], bin[8], rnk[8];
    unsigned pk[8];
#pragma unroll
    for (int k = 0; k < 8; ++k) {
        int e = eb + k * 1024 + t;
        int s = ei[e];
        int d = ei[N_EDGES + e];
        float2 a = ea[e];
        int b = (unsigned)d / NPB;
        int dn = d - b * NPB;
        wd0[k] = s | (dn << 17);
        pk[k] = ((unsigned)f2bf(a.y) << 16) | f2bf(a.x);
        bin[k] = b;
        rnk[k] = atomicAdd(&cnt[b], 1);
    }
    __syncthreads();
    if (t < NB) base[t] = bbase[t] + cm[t * NCH + c];
    __syncthreads();
#pragma unroll
    for (int k = 0; k < 8; ++k)
        rec[base[bin[k]] + rnk[k]] = make_int2(wd0[k], (int)pk[k]);
}

// One atomic-rank pass, then scan + direct positioned write.
__global__ __launch_bounds__(1024) void k_sort(int2* __restrict__ rec,
                                               const int* __restrict__ bbase,
                                               int* __restrict__ row) {
    __shared__ int cnt[256], tmp[256], ebase[256];
    int b = blockIdx.x, t = threadIdx.x;
    int n0 = b * NPB;
    int beg = bbase[b], end = bbase[b + 1], m = end - beg;
    if (t < 256) cnt[t] = 0;
    __syncthreads();
    int2 rv[12];
    int dr[12];
    int cv = 0;
    for (int i = t; i < m; i += 1024) {
        int2 r = rec[beg + i];
        int dn = ((unsigned)r.x >> 17) & 0xFF;
        int rnk = atomicAdd(&cnt[dn], 1);
        if (cv < 12) { rv[cv] = r; dr[cv] = dn | (rnk << 8); }
        cv++;                 // m <= 12288 always (bucket ~8192 + 45 sigma)
    }
    __syncthreads();
    int* s = cnt; int* d = tmp;
    for (int off = 1; off < 256; off <<= 1) {
        int v = 0;
        if (t < 256) v = s[t] + (t >= off ? s[t - off] : 0);
        __syncthreads();
        if (t < 256) d[t] = v;
        __syncthreads();
        int* tp = s; s = d; d = tp;
    }
    if (t < 256) ebase[t] = t ? s[t - 1] : 0;
    __syncthreads();
    if (t < NPB) row[n0 + t] = beg + ebase[t];
    int ncv = cv < 12 ? cv : 12;
    for (int k = 0; k < ncv; ++k) {
        int dn = dr[k] & 0xFF;
        int rnk = dr[k] >> 8;
        rec[beg + ebase[dn] + rnk] = rv[k];
    }
}

// pack two f32 (this lane = even j, partner = j+1) into fp8x2 and store
__device__ __forceinline__ void store_fp8_pair(unsigned short* __restrict__ hout,
                                               int n, int j, float acc) {
    float p = __shfl_xor(acc, 1);   // even j: p = acc of j+1
    if (!(j & 1)) {
        float2 v = make_float2(acc, p);
        __hip_fp8x2_storage_t s2 = __hip_cvt_float2_to_fp8x2(v, __HIP_SATFINITE, __HIP_E4M3);
        hout[(n << 4) + (j >> 1)] = (unsigned short)s2;
    }
}

__global__ void k_transform0(const float* __restrict__ x, const float* __restrict__ W0,
                             const float* __restrict__ as_w, const float* __restrict__ ad_w,
                             unsigned short* __restrict__ hout, float* __restrict__ as_arr,
                             float* __restrict__ ad_arr) {
    int tid = blockIdx.x * 256 + threadIdx.x;
    int j = tid & 31;
    int n = tid >> 5;
    float acc = x[n] * W0[j];
    store_fp8_pair(hout, n, j, acc);
    float v1 = acc * as_w[j], v2 = acc * ad_w[j];
#pragma unroll
    for (int m = 16; m >= 1; m >>= 1) {
        v1 += __shfl_xor(v1, m);
        v2 += __shfl_xor(v2, m);
    }
    if (j == 0) { as_arr[n] = v1; ad_arr[n] = v2; }
}

__global__ void k_transform(const float* __restrict__ hin, const float* __restrict__ W,
                            const float* __restrict__ as_w, const float* __restrict__ ad_w,
                            unsigned short* __restrict__ hout, float* __restrict__ as_arr,
                            float* __restrict__ ad_arr) {
    __shared__ float Wl[1024];
    int t = threadIdx.x;
#pragma unroll
    for (int i = 0; i < 4; ++i) Wl[t + i * 256] = W[t + i * 256];
    __syncthreads();
    int tid = blockIdx.x * 256 + t;
    int j = tid & 31;
    int n = tid >> 5;
    float hv = hin[tid];
    float acc = 0.f;
#pragma unroll
    for (int k = 0; k < 32; ++k) acc += __shfl(hv, k, 32) * Wl[k * 32 + j];
    store_fp8_pair(hout, n, j, acc);
    float v1 = acc * as_w[j], v2 = acc * ad_w[j];
#pragma unroll
    for (int m = 16; m >= 1; m >>= 1) {
        v1 += __shfl_xor(v1, m);
        v2 += __shfl_xor(v2, m);
    }
    if (j == 0) { as_arr[n] = v1; ad_arr[n] = v2; }
}

// accumulate 4 fp8 values (one 32-bit word) via HW packed fp8->half cvt
__device__ __forceinline__ void acc4_fp8(float w, unsigned word, float* acc) {
    __half2_raw h01 = __hip_cvt_fp8x2_to_halfraw2((__hip_fp8x2_storage_t)(word & 0xFFFFu), __HIP_E4M3);
    __half2_raw h23 = __hip_cvt_fp8x2_to_halfraw2((__hip_fp8x2_storage_t)(word >> 16), __HIP_E4M3);
    acc[0] += w * __half2float(__ushort_as_half(((__half_raw)h01.x).x));
    acc[1] += w * __half2float(__ushort_as_half(((__half_raw)h01.y).x));
    acc[2] += w * __half2float(__ushort_as_half(((__half_raw)h23.x).x));
    acc[3] += w * __half2float(__ushort_as_half(((__half_raw)h23.y).x));
}

__device__ __forceinline__ void edge_body(int2 r, const int2* __restrict__ hv,
                                          const float* __restrict__ as_arr,
                                          float c_dst, float f0, float f1, int dl,
                                          float* acc, float& den, float& esum) {
    int s = r.x & SRCMASK;
    int2 h = hv[(s << 2) + dl];   // 8 fp8 = dims dl*8 .. dl*8+7
    float a = as_arr[s];
    float ax = __uint_as_float((unsigned)r.y << 16);
    float ay = __uint_as_float((unsigned)r.y & 0xFFFF0000u);
    float ed = fmaf(ax, f0, ay * f1);
    float lg = a + c_dst + ed;
    lg = fmaxf(lg, NEG * lg);
    float w = __expf(lg);
    den += w;
    esum += ed;
    acc4_fp8(w, (unsigned)h.x, acc);
    acc4_fp8(w, (unsigned)h.y, acc + 4);
}

// One wave per node: 16 edge slots x 4 dim-lanes (8 dims each; int2 = 8 fp8).
// hT is 2.75 MB -> per-XCD-L2-resident; random row touches stop missing to HBM.
__global__ void k_gather(const unsigned short* __restrict__ hT, const int2* __restrict__ rec,
                         const int* __restrict__ row,
                         const float* __restrict__ as_arr, const float* __restrict__ ad_arr,
                         const float* __restrict__ fold, const float* __restrict__ bias,
                         float* __restrict__ out, int do_relu) {
    const int2* hv = (const int2*)hT;   // row n = hv[n*4 + dl]
    int lane = threadIdx.x & 63;
    int n = blockIdx.x * 4 + (threadIdx.x >> 6);
    int slot = lane >> 2;     // 0..15
    int dl = lane & 3;        // 0..3
    int beg = row[n], end = row[n + 1];
    float c_dst = ad_arr[n];
    float f0 = fold[0], f1 = fold[1];
    float acc[8] = {0.f, 0.f, 0.f, 0.f, 0.f, 0.f, 0.f, 0.f};
    float den = 0.f, esum = 0.f;
    int e = beg;
    for (; e + 32 <= end; e += 32) {
        int2 r0 = rec[e + slot];
        int2 r1 = rec[e + 16 + slot];
        edge_body(r0, hv, as_arr, c_dst, f0, f1, dl, acc, den, esum);
        edge_body(r1, hv, as_arr, c_dst, f0, f1, dl, acc, den, esum);
    }
    for (; e + 16 <= end; e += 16) {
        int2 r = rec[e + slot];
        edge_body(r, hv, as_arr, c_dst, f0, f1, dl, acc, den, esum);
    }
    {
        int ee = e + slot;
        if (ee < end)
            edge_body(rec[ee], hv, as_arr, c_dst, f0, f1, dl, acc, den, esum);
    }
#pragma unroll
    for (int m = 4; m <= 32; m <<= 1) {
#pragma unroll
        for (int k = 0; k < 8; ++k) acc[k] += __shfl_xor(acc[k], m);
        den += __shfl_xor(den, m);
        esum += __shfl_xor(esum, m);
    }
    // self loop: edge attr = mean of incoming (0 if deg==0), src = n
    int dg = end - beg;
    float el = esum / fmaxf((float)dg, 1.0f);
    float lg = as_arr[n] + c_dst + el;
    lg = fmaxf(lg, NEG * lg);
    float w = __expf(lg);
    den += w;
    int2 hs = hv[(n << 2) + dl];
    acc4_fp8(w, (unsigned)hs.x, acc);
    acc4_fp8(w, (unsigned)hs.y, acc + 4);
    float rden = 1.0f / den;
    float o[8];
#pragma unroll
    for (int k = 0; k < 8; ++k) {
        o[k] = acc[k] * rden + bias[8 * dl + k];
        if (do_relu) o[k] = fmaxf(o[k], 0.f);
    }
    if (slot == 0) {
        float4 v0 = {o[0], o[1], o[2], o[3]};
        float4 v1 = {o[4], o[5], o[6], o[7]};
        *(float4*)(out + (n << 5) + 8 * dl) = v0;
        *(float4*)(out + (n << 5) + 8 * dl + 4) = v1;
    }
}

__global__ void k_pool(const float* __restrict__ h, const float* __restrict__ lw,
                       const float* __restrict__ lb, float* __restrict__ out) {
    int lane = threadIdx.x & 63;
    int g = blockIdx.x * 4 + (threadIdx.x >> 6);
    int j = lane & 31;
    int half = lane >> 5;
    const float* base = h + (size_t)g * NPG * HID;
    float acc = 0.f;
    for (int i = half; i < NPG; i += 2) acc += base[i * HID + j];
    acc += __shfl_xor(acc, 32);
    float v = acc * lw[j];
#pragma unroll
    for (int m = 16; m >= 1; m >>= 1) v += __shfl_xor(v, m);
    if (lane == 0) out[g] = fmaxf(v + lb[0], 0.f);
}

extern "C" void kernel_launch(void* const* d_in, const int* in_sizes, int n_in,
                              void* d_out, int out_size, void* d_ws, size_t ws_size,
                              hipStream_t stream) {
    const float* x        = (const float*)d_in[0];
    const int*   ei       = (const int*)d_in[1];
    const float* eattr    = (const float*)d_in[2];
    const float* W0       = (const float*)d_in[3];
    const float* Ws       = (const float*)d_in[4];
    const float* att_src  = (const float*)d_in[5];
    const float* att_dst  = (const float*)d_in[6];
    const float* We       = (const float*)d_in[7];
    const float* att_edge = (const float*)d_in[8];
    const float* bias     = (const float*)d_in[9];
    const float* lin_w    = (const float*)d_in[10];
    const float* lin_b    = (const float*)d_in[11];
    float* out = (float*)d_out;

    char* w = (char*)d_ws;
    int2*           rec    = (int2*)(w + O_REC);
    int*            cm     = (int*)(w + O_CM);
    unsigned short* hT     = (unsigned short*)(w + O_HT);
    float*          hB     = (float*)(w + O_HB);
    float*          as_arr = (float*)(w + O_AS);
    float*          ad_arr = (float*)(w + O_AD);
    int*            row    = (int*)(w + O_ROW);
    int*            btot   = (int*)(w + O_BTOT);
    int*            bbase  = (int*)(w + O_BBASE);
    float*          fold   = (float*)(w + O_FOLD);

    // ---- CSR build (atomic-free, write-clustered, single 8B stream) ----
    k_hist<<<NCH, 1024, 0, stream>>>(ei + N_EDGES, cm);
    k_scanchunks<<<NB, 512, 0, stream>>>(cm, btot);
    k_scanbuckets<<<1, NB, 0, stream>>>(btot, bbase, row, We, att_edge, fold);
    k_place<<<NCH, 1024, 0, stream>>>(ei, (const float2*)eattr, cm, bbase, rec);
    k_sort<<<NB, 1024, 0, stream>>>(rec, bbase, row);

    // ---- layer 0 ----
    k_transform0<<<N_NODES * HID / 256, 256, 0, stream>>>(x, W0, att_src, att_dst,
                                                          hT, as_arr, ad_arr);
    k_gather<<<N_NODES / 4, 256, 0, stream>>>(hT, rec, row, as_arr, ad_arr,
                                              fold, bias, hB, 1);
    // ---- layers 1..3 ----
    for (int l = 1; l < 4; ++l) {
        k_transform<<<N_NODES * HID / 256, 256, 0, stream>>>(
            hB, Ws + (size_t)(l - 1) * HID * HID, att_src + l * HID, att_dst + l * HID,
            hT, as_arr, ad_arr);
        k_gather<<<N_NODES / 4, 256, 0, stream>>>(hT, rec, row, as_arr, ad_arr,
                                                  fold + 2 * l, bias + l * HID, hB,
                                                  (l < 3) ? 1 : 0);
    }

    // ---- pool + linear + relu ----
    k_pool<<<B_GR / 4, 256, 0, stream>>>(hB, lin_w, lin_b, out);
}

// Round 13
// 517.841 us; speedup vs baseline: 1.5412x; 1.5412x over previous
//
#include <hip/hip_runtime.h>

#define N_NODES 86016
#define N_EDGES 4194304
#define HID 32
#define B_GR 1024
#define NPG 84
#define NEG 0.2f

#define NCH 512       // chunks
#define CHE 8192      // edges per chunk; NCH*CHE == N_EDGES
#define NB  512       // dst buckets
#define NPB 168       // nodes per bucket; NB*NPB == N_NODES
#define SRCMASK 0x1FFFF   // 17 bits (N_NODES < 2^17)

typedef float floatx2 __attribute__((ext_vector_type(2)));

// ---- workspace layout (bytes) ----
// Edge record: int2 { src | (dn<<17), (bf16(ea.y)<<16)|bf16(ea.x) } = 8 B.
// hT: N x 32 fp8-e4m3 (32 B/row) = 2.75 MB -> fits per-XCD 4 MiB L2.
constexpr size_t O_REC   = 0;                                    // E * 8
constexpr size_t O_CM    = O_REC  + (size_t)N_EDGES * 8;         // NB*NCH int
constexpr size_t O_HT    = O_CM   + (size_t)NB * NCH * 4;        // N*32 fp8
constexpr size_t O_HB    = O_HT   + (size_t)N_NODES * HID;       // N*32 f32
constexpr size_t O_AS    = O_HB   + (size_t)N_NODES * HID * 4;   // N f32
constexpr size_t O_AD    = O_AS   + (size_t)N_NODES * 4;         // N f32
constexpr size_t O_ROW   = O_AD   + (size_t)N_NODES * 4;         // N+1 int
constexpr size_t O_BTOT  = O_ROW  + (size_t)(N_NODES + 1) * 4 + 12; // NB int
constexpr size_t O_BBASE = O_BTOT + (size_t)NB * 4;              // NB+1 int
constexpr size_t O_FOLD  = O_BBASE + (size_t)(NB + 1) * 4 + 12;  // 8 f32

__device__ __forceinline__ unsigned short f2bf(float f) {
    unsigned u = __float_as_uint(f);
    u += 0x7FFFu + ((u >> 16) & 1u);      // round-to-nearest-even
    return (unsigned short)(u >> 16);
}

// ---- CSR build, atomic-free (global), single 8B stream ----
__global__ __launch_bounds__(1024) void k_hist(const int* __restrict__ dst, int* __restrict__ cm) {
    __shared__ int cnt[NB];
    int t = threadIdx.x, c = blockIdx.x;
    if (t < NB) cnt[t] = 0;
    __syncthreads();
    int base = c * CHE;
#pragma unroll
    for (int k = 0; k < 8; ++k) {
        int d = dst[base + k * 1024 + t];
        atomicAdd(&cnt[(unsigned)d / NPB], 1);
    }
    __syncthreads();
    if (t < NB) cm[t * NCH + c] = cnt[t];
}

__global__ __launch_bounds__(512) void k_scanchunks(int* __restrict__ cm, int* __restrict__ btot) {
    __shared__ int sa[NCH], sb[NCH];
    int b = blockIdx.x, t = threadIdx.x;
    sa[t] = cm[b * NCH + t];
    __syncthreads();
    int* s = sa; int* d = sb;
    for (int off = 1; off < NCH; off <<= 1) {
        d[t] = s[t] + (t >= off ? s[t - off] : 0);
        __syncthreads();
        int* tmp = s; s = d; d = tmp;
    }
    cm[b * NCH + t] = t ? s[t - 1] : 0;
    if (t == 0) btot[b] = s[NCH - 1];
}

// bucket-total scan (+ inlined fold computation on threads 0..7)
__global__ void k_scanbuckets(const int* __restrict__ btot, int* __restrict__ bbase,
                              int* __restrict__ row,
                              const float* __restrict__ We, const float* __restrict__ ae,
                              float* __restrict__ fold) {
    __shared__ int sa[NB], sb[NB];
    int t = threadIdx.x;
    if (t < 8) {
        int l = t >> 1, c = t & 1;
        float s = 0.f;
        for (int j = 0; j < 32; ++j) s += We[l * 64 + c * 32 + j] * ae[l * 32 + j];
        fold[t] = s;
    }
    sa[t] = btot[t];
    __syncthreads();
    int* s = sa; int* d = sb;
    for (int off = 1; off < NB; off <<= 1) {
        d[t] = s[t] + (t >= off ? s[t - off] : 0);
        __syncthreads();
        int* tmp = s; s = d; d = tmp;
    }
    bbase[t] = t ? s[t - 1] : 0;
    if (t == NB - 1) { bbase[NB] = s[NB - 1]; row[N_NODES] = s[NB - 1]; }
}

// R8-style place: register-staged batch of 8 edges, rank in LDS, batched writes.
__global__ __launch_bounds__(1024) void k_place(const int* __restrict__ ei,
                                                const float2* __restrict__ ea,
                                                const int* __restrict__ cm,
                                                const int* __restrict__ bbase,
                                                int2* __restrict__ rec) {
    __shared__ int cnt[NB];
    __shared__ int base[NB];
    int t = threadIdx.x, c = blockIdx.x;
    if (t < NB) cnt[t] = 0;
    __syncthreads();
    int eb = c * CHE;
    int wd0[8], bin[8], rnk[8];
    unsigned pk[8];
#pragma unroll
    for (int k = 0; k < 8; ++k) {
        int e = eb + k * 1024 + t;
        int s = ei[e];
        int d = ei[N_EDGES + e];
        float2 a = ea[e];
        int b = (unsigned)d / NPB;
        int dn = d - b * NPB;
        wd0[k] = s | (dn << 17);
        pk[k] = ((unsigned)f2bf(a.y) << 16) | f2bf(a.x);
        bin[k] = b;
        rnk[k] = atomicAdd(&cnt[b], 1);
    }
    __syncthreads();
    if (t < NB) base[t] = bbase[t] + cm[t * NCH + c];
    __syncthreads();
#pragma unroll
    for (int k = 0; k < 8; ++k)
        rec[base[bin[k]] + rnk[k]] = make_int2(wd0[k], (int)pk[k]);
}

// One atomic-rank pass, then scan + direct positioned write.
__global__ __launch_bounds__(1024) void k_sort(int2* __restrict__ rec,
                                               const int* __restrict__ bbase,
                                               int* __restrict__ row) {
    __shared__ int cnt[256], tmp[256], ebase[256];
    int b = blockIdx.x, t = threadIdx.x;
    int n0 = b * NPB;
    int beg = bbase[b], end = bbase[b + 1], m = end - beg;
    if (t < 256) cnt[t] = 0;
    __syncthreads();
    int2 rv[12];
    int dr[12];
    int cv = 0;
    for (int i = t; i < m; i += 1024) {
        int2 r = rec[beg + i];
        int dn = ((unsigned)r.x >> 17) & 0xFF;
        int rnk = atomicAdd(&cnt[dn], 1);
        if (cv < 12) { rv[cv] = r; dr[cv] = dn | (rnk << 8); }
        cv++;                 // m <= 12288 always (bucket ~8192 + 45 sigma)
    }
    __syncthreads();
    int* s = cnt; int* d = tmp;
    for (int off = 1; off < 256; off <<= 1) {
        int v = 0;
        if (t < 256) v = s[t] + (t >= off ? s[t - off] : 0);
        __syncthreads();
        if (t < 256) d[t] = v;
        __syncthreads();
        int* tp = s; s = d; d = tp;
    }
    if (t < 256) ebase[t] = t ? s[t - 1] : 0;
    __syncthreads();
    if (t < NPB) row[n0 + t] = beg + ebase[t];
    int ncv = cv < 12 ? cv : 12;
    for (int k = 0; k < ncv; ++k) {
        int dn = dr[k] & 0xFF;
        int rnk = dr[k] >> 8;
        rec[beg + ebase[dn] + rnk] = rv[k];
    }
}

// pack two f32 (this lane = even j, partner = j+1) into fp8x2 via the NATIVE
// v_cvt_pk_fp8_f32 and store 16 bits.
__device__ __forceinline__ void store_fp8_pair(unsigned short* __restrict__ hout,
                                               int n, int j, float acc) {
    float p = __shfl_xor(acc, 1);   // even j: p = acc of j+1
    if (!(j & 1)) {
        int pk = __builtin_amdgcn_cvt_pk_fp8_f32(acc, p, 0, false);
        hout[(n << 4) + (j >> 1)] = (unsigned short)pk;
    }
}

__global__ void k_transform0(const float* __restrict__ x, const float* __restrict__ W0,
                             const float* __restrict__ as_w, const float* __restrict__ ad_w,
                             unsigned short* __restrict__ hout, float* __restrict__ as_arr,
                             float* __restrict__ ad_arr) {
    int tid = blockIdx.x * 256 + threadIdx.x;
    int j = tid & 31;
    int n = tid >> 5;
    float acc = x[n] * W0[j];
    store_fp8_pair(hout, n, j, acc);
    float v1 = acc * as_w[j], v2 = acc * ad_w[j];
#pragma unroll
    for (int m = 16; m >= 1; m >>= 1) {
        v1 += __shfl_xor(v1, m);
        v2 += __shfl_xor(v2, m);
    }
    if (j == 0) { as_arr[n] = v1; ad_arr[n] = v2; }
}

__global__ void k_transform(const float* __restrict__ hin, const float* __restrict__ W,
                            const float* __restrict__ as_w, const float* __restrict__ ad_w,
                            unsigned short* __restrict__ hout, float* __restrict__ as_arr,
                            float* __restrict__ ad_arr) {
    __shared__ float Wl[1024];
    int t = threadIdx.x;
#pragma unroll
    for (int i = 0; i < 4; ++i) Wl[t + i * 256] = W[t + i * 256];
    __syncthreads();
    int tid = blockIdx.x * 256 + t;
    int j = tid & 31;
    int n = tid >> 5;
    float hv = hin[tid];
    float acc = 0.f;
#pragma unroll
    for (int k = 0; k < 32; ++k) acc += __shfl(hv, k, 32) * Wl[k * 32 + j];
    store_fp8_pair(hout, n, j, acc);
    float v1 = acc * as_w[j], v2 = acc * ad_w[j];
#pragma unroll
    for (int m = 16; m >= 1; m >>= 1) {
        v1 += __shfl_xor(v1, m);
        v2 += __shfl_xor(v2, m);
    }
    if (j == 0) { as_arr[n] = v1; ad_arr[n] = v2; }
}

// accumulate 4 fp8 values (one 32-bit word) via NATIVE v_cvt_pk_f32_fp8
// (2 f32 per instruction).
__device__ __forceinline__ void acc4_fp8(float w, int word, float* acc) {
    floatx2 v01 = __builtin_amdgcn_cvt_pk_f32_fp8(word, false);
    floatx2 v23 = __builtin_amdgcn_cvt_pk_f32_fp8(word, true);
    acc[0] = fmaf(w, v01.x, acc[0]);
    acc[1] = fmaf(w, v01.y, acc[1]);
    acc[2] = fmaf(w, v23.x, acc[2]);
    acc[3] = fmaf(w, v23.y, acc[3]);
}

__device__ __forceinline__ void edge_body(int2 r, const int2* __restrict__ hv,
                                          const float* __restrict__ as_arr,
                                          float c_dst, float f0, float f1, int dl,
                                          float* acc, float& den, float& esum) {
    int s = r.x & SRCMASK;
    int2 h = hv[(s << 2) + dl];   // 8 fp8 = dims dl*8 .. dl*8+7
    float a = as_arr[s];
    float ax = __uint_as_float((unsigned)r.y << 16);
    float ay = __uint_as_float((unsigned)r.y & 0xFFFF0000u);
    float ed = fmaf(ax, f0, ay * f1);
    float lg = a + c_dst + ed;
    lg = fmaxf(lg, NEG * lg);
    float w = __expf(lg);
    den += w;
    esum += ed;
    acc4_fp8(w, h.x, acc);
    acc4_fp8(w, h.y, acc + 4);
}

// One wave per node: 16 edge slots x 4 dim-lanes (8 dims each; int2 = 8 fp8).
// hT is 2.75 MB -> per-XCD-L2-resident (FETCH confirmed 38.5 MB in R11).
__global__ void k_gather(const unsigned short* __restrict__ hT, const int2* __restrict__ rec,
                         const int* __restrict__ row,
                         const float* __restrict__ as_arr, const float* __restrict__ ad_arr,
                         const float* __restrict__ fold, const float* __restrict__ bias,
                         float* __restrict__ out, int do_relu) {
    const int2* hv = (const int2*)hT;   // row n = hv[n*4 + dl]
    int lane = threadIdx.x & 63;
    int n = blockIdx.x * 4 + (threadIdx.x >> 6);
    int slot = lane >> 2;     // 0..15
    int dl = lane & 3;        // 0..3
    int beg = row[n], end = row[n + 1];
    float c_dst = ad_arr[n];
    float f0 = fold[0], f1 = fold[1];
    float acc[8] = {0.f, 0.f, 0.f, 0.f, 0.f, 0.f, 0.f, 0.f};
    float den = 0.f, esum = 0.f;
    int e = beg;
    for (; e + 32 <= end; e += 32) {
        int2 r0 = rec[e + slot];
        int2 r1 = rec[e + 16 + slot];
        edge_body(r0, hv, as_arr, c_dst, f0, f1, dl, acc, den, esum);
        edge_body(r1, hv, as_arr, c_dst, f0, f1, dl, acc, den, esum);
    }
    for (; e + 16 <= end; e += 16) {
        int2 r = rec[e + slot];
        edge_body(r, hv, as_arr, c_dst, f0, f1, dl, acc, den, esum);
    }
    {
        int ee = e + slot;
        if (ee < end)
            edge_body(rec[ee], hv, as_arr, c_dst, f0, f1, dl, acc, den, esum);
    }
#pragma unroll
    for (int m = 4; m <= 32; m <<= 1) {
#pragma unroll
        for (int k = 0; k < 8; ++k) acc[k] += __shfl_xor(acc[k], m);
        den += __shfl_xor(den, m);
        esum += __shfl_xor(esum, m);
    }
    // self loop: edge attr = mean of incoming (0 if deg==0), src = n
    int dg = end - beg;
    float el = esum / fmaxf((float)dg, 1.0f);
    float lg = as_arr[n] + c_dst + el;
    lg = fmaxf(lg, NEG * lg);
    float w = __expf(lg);
    den += w;
    int2 hs = hv[(n << 2) + dl];
    acc4_fp8(w, hs.x, acc);
    acc4_fp8(w, hs.y, acc + 4);
    float rden = 1.0f / den;
    float o[8];
#pragma unroll
    for (int k = 0; k < 8; ++k) {
        o[k] = acc[k] * rden + bias[8 * dl + k];
        if (do_relu) o[k] = fmaxf(o[k], 0.f);
    }
    if (slot == 0) {
        float4 v0 = {o[0], o[1], o[2], o[3]};
        float4 v1 = {o[4], o[5], o[6], o[7]};
        *(float4*)(out + (n << 5) + 8 * dl) = v0;
        *(float4*)(out + (n << 5) + 8 * dl + 4) = v1;
    }
}

__global__ void k_pool(const float* __restrict__ h, const float* __restrict__ lw,
                       const float* __restrict__ lb, float* __restrict__ out) {
    int lane = threadIdx.x & 63;
    int g = blockIdx.x * 4 + (threadIdx.x >> 6);
    int j = lane & 31;
    int half = lane >> 5;
    const float* base = h + (size_t)g * NPG * HID;
    float acc = 0.f;
    for (int i = half; i < NPG; i += 2) acc += base[i * HID + j];
    acc += __shfl_xor(acc, 32);
    float v = acc * lw[j];
#pragma unroll
    for (int m = 16; m >= 1; m >>= 1) v += __shfl_xor(v, m);
    if (lane == 0) out[g] = fmaxf(v + lb[0], 0.f);
}

extern "C" void kernel_launch(void* const* d_in, const int* in_sizes, int n_in,
                              void* d_out, int out_size, void* d_ws, size_t ws_size,
                              hipStream_t stream) {
    const float* x        = (const float*)d_in[0];
    const int*   ei       = (const int*)d_in[1];
    const float* eattr    = (const float*)d_in[2];
    const float* W0       = (const float*)d_in[3];
    const float* Ws       = (const float*)d_in[4];
    const float* att_src  = (const float*)d_in[5];
    const float* att_dst  = (const float*)d_in[6];
    const float* We       = (const float*)d_in[7];
    const float* att_edge = (const float*)d_in[8];
    const float* bias     = (const float*)d_in[9];
    const float* lin_w    = (const float*)d_in[10];
    const float* lin_b    = (const float*)d_in[11];
    float* out = (float*)d_out;

    char* w = (char*)d_ws;
    int2*           rec    = (int2*)(w + O_REC);
    int*            cm     = (int*)(w + O_CM);
    unsigned short* hT     = (unsigned short*)(w + O_HT);
    float*          hB     = (float*)(w + O_HB);
    float*          as_arr = (float*)(w + O_AS);
    float*          ad_arr = (float*)(w + O_AD);
    int*            row    = (int*)(w + O_ROW);
    int*            btot   = (int*)(w + O_BTOT);
    int*            bbase  = (int*)(w + O_BBASE);
    float*          fold   = (float*)(w + O_FOLD);

    // ---- CSR build (atomic-free, write-clustered, single 8B stream) ----
    k_hist<<<NCH, 1024, 0, stream>>>(ei + N_EDGES, cm);
    k_scanchunks<<<NB, 512, 0, stream>>>(cm, btot);
    k_scanbuckets<<<1, NB, 0, stream>>>(btot, bbase, row, We, att_edge, fold);
    k_place<<<NCH, 1024, 0, stream>>>(ei, (const float2*)eattr, cm, bbase, rec);
    k_sort<<<NB, 1024, 0, stream>>>(rec, bbase, row);

    // ---- layer 0 ----
    k_transform0<<<N_NODES * HID / 256, 256, 0, stream>>>(x, W0, att_src, att_dst,
                                                          hT, as_arr, ad_arr);
    k_gather<<<N_NODES / 4, 256, 0, stream>>>(hT, rec, row, as_arr, ad_arr,
                                              fold, bias, hB, 1);
    // ---- layers 1..3 ----
    for (int l = 1; l < 4; ++l) {
        k_transform<<<N_NODES * HID / 256, 256, 0, stream>>>(
            hB, Ws + (size_t)(l - 1) * HID * HID, att_src + l * HID, att_dst + l * HID,
            hT, as_arr, ad_arr);
        k_gather<<<N_NODES / 4, 256, 0, stream>>>(hT, rec, row, as_arr, ad_arr,
                                                  fold + 2 * l, bias + l * HID, hB,
                                                  (l < 3) ? 1 : 0);
    }

    // ---- pool + linear + relu ----
    k_pool<<<B_GR / 4, 256, 0, stream>>>(hB, lin_w, lin_b, out);
}